// Round 1
// baseline (467.135 us; speedup 1.0000x reference)
//
#include <hip/hip_runtime.h>
#include <math.h>

// Problem constants (fixed by the reference file)
#define OUT_H 7
#define OUT_W 7
#define GS 2                      // SAMPLE_NUM
#define NBINS (OUT_H * OUT_W)     // 49
#define NSAMP (GS * GS)           // 4
#define SPATIAL_SCALE 0.25f
#define B_ 2
#define C_ 256
#define H_ 200
#define W_ 200
#define R_ 1000

struct alignas(16) Samp {
    int o0, o1, o2, o3;     // absolute offsets within features (incl. batch plane)
    float w0, w1, w2, w3;   // bilinear weights * 0.25 (sample mean) * valid
};

// ---- shared device helper: compute one sample's offsets/weights ----
__device__ __forceinline__ Samp compute_samp(const float* __restrict__ rois,
                                             int r, int ph, int pw, int s) {
    const float* roi = rois + r * 6;
    int   b     = (int)roi[0];
    float cx    = roi[1] * SPATIAL_SCALE - 0.5f;   // ALIGNED => offset 0.5
    float cy    = roi[2] * SPATIAL_SCALE - 0.5f;
    float rw    = roi[3] * SPATIAL_SCALE;
    float rh    = roi[4] * SPATIAL_SCALE;
    float theta = roi[5];                           // CLOCKWISE == False

    float bin_h = rh * (1.0f / OUT_H);
    float bin_w = rw * (1.0f / OUT_W);

    int iy = s / GS, ix = s % GS;
    float yy = -rh * 0.5f + ((float)ph + ((float)iy + 0.5f) * (1.0f / GS)) * bin_h;
    float xx = -rw * 0.5f + ((float)pw + ((float)ix + 0.5f) * (1.0f / GS)) * bin_w;

    float st = sinf(theta), ct = cosf(theta);
    float x = yy * st + xx * ct + cx;
    float y = yy * ct - xx * st + cy;

    bool valid = (y > -1.0f) && (y < (float)H_) && (x > -1.0f) && (x < (float)W_);
    y = fmaxf(y, 0.0f);
    x = fmaxf(x, 0.0f);

    int yl = (int)y;            // y >= 0 => trunc == floor
    int xl = (int)x;
    int yh; float ly;
    if (yl >= H_ - 1) { yl = H_ - 1; yh = H_ - 1; ly = 0.0f; }
    else              { yh = yl + 1; ly = y - (float)yl; }
    int xh; float lx;
    if (xl >= W_ - 1) { xl = W_ - 1; xh = W_ - 1; lx = 0.0f; }
    else              { xh = xl + 1; lx = x - (float)xl; }

    float hy = 1.0f - ly, hx = 1.0f - lx;
    float scale = valid ? (1.0f / NSAMP) : 0.0f;   // fold mean + valid mask

    Samp sp;
    int base = b * (C_ * H_ * W_);
    sp.o0 = base + yl * W_ + xl;
    sp.o1 = base + yl * W_ + xh;
    sp.o2 = base + yh * W_ + xl;
    sp.o3 = base + yh * W_ + xh;
    sp.w0 = hy * hx * scale;
    sp.w1 = hy * lx * scale;
    sp.w2 = ly * hx * scale;
    sp.w3 = ly * lx * scale;
    return sp;
}

// ---- kernel 1: precompute sample table (R*49*4 = 196,000 entries, 6.27 MB) ----
__global__ __launch_bounds__(256)
void precompute_kernel(const float* __restrict__ rois, Samp* __restrict__ tab) {
    int idx = blockIdx.x * blockDim.x + threadIdx.x;
    if (idx >= R_ * NBINS * NSAMP) return;
    int s   = idx & (NSAMP - 1);
    int bin = (idx >> 2) % NBINS;
    int r   = idx / (NBINS * NSAMP);
    tab[idx] = compute_samp(rois, r, bin / OUT_W, bin % OUT_W, s);
}

// ---- kernel 2: pure gather, one thread per output element ----
__global__ __launch_bounds__(256)
void gather_kernel(const float* __restrict__ feat,
                   const Samp* __restrict__ tab,
                   float* __restrict__ out) {
    int tid = blockIdx.x * blockDim.x + threadIdx.x;
    if (tid >= R_ * C_ * NBINS) return;
    int bin = tid % NBINS;
    int rc  = tid / NBINS;
    int c   = rc % C_;
    int r   = rc / C_;

    const Samp* sp = tab + (r * NBINS + bin) * NSAMP;
    int coff = c * (H_ * W_);

    float acc = 0.0f;
#pragma unroll
    for (int s = 0; s < NSAMP; ++s) {
        Samp t = sp[s];
        acc += t.w0 * feat[coff + t.o0];
        acc += t.w1 * feat[coff + t.o1];
        acc += t.w2 * feat[coff + t.o2];
        acc += t.w3 * feat[coff + t.o3];
    }
    out[tid] = acc;
}

// ---- fallback: monolithic kernel (if workspace too small for the table) ----
__global__ __launch_bounds__(256)
void mono_kernel(const float* __restrict__ feat,
                 const float* __restrict__ rois,
                 float* __restrict__ out) {
    int tid = blockIdx.x * blockDim.x + threadIdx.x;
    if (tid >= R_ * C_ * NBINS) return;
    int bin = tid % NBINS;
    int rc  = tid / NBINS;
    int c   = rc % C_;
    int r   = rc / C_;
    int coff = c * (H_ * W_);

    float acc = 0.0f;
#pragma unroll
    for (int s = 0; s < NSAMP; ++s) {
        Samp t = compute_samp(rois, r, bin / OUT_W, bin % OUT_W, s);
        acc += t.w0 * feat[coff + t.o0];
        acc += t.w1 * feat[coff + t.o1];
        acc += t.w2 * feat[coff + t.o2];
        acc += t.w3 * feat[coff + t.o3];
    }
    out[tid] = acc;
}

extern "C" void kernel_launch(void* const* d_in, const int* in_sizes, int n_in,
                              void* d_out, int out_size, void* d_ws, size_t ws_size,
                              hipStream_t stream) {
    const float* feat = (const float*)d_in[0];
    const float* rois = (const float*)d_in[1];
    float* out = (float*)d_out;

    const size_t tab_bytes = (size_t)R_ * NBINS * NSAMP * sizeof(Samp);
    const int n_out = R_ * C_ * NBINS;
    const int gather_blocks = (n_out + 255) / 256;

    if (ws_size >= tab_bytes) {
        Samp* tab = (Samp*)d_ws;
        const int n_samp = R_ * NBINS * NSAMP;
        precompute_kernel<<<(n_samp + 255) / 256, 256, 0, stream>>>(rois, tab);
        gather_kernel<<<gather_blocks, 256, 0, stream>>>(feat, tab, out);
    } else {
        mono_kernel<<<gather_blocks, 256, 0, stream>>>(feat, rois, out);
    }
}

// Round 2
// 219.196 us; speedup vs baseline: 2.1311x; 2.1311x over previous
//
#include <hip/hip_runtime.h>
#include <math.h>

// Problem constants (fixed by the reference file)
#define OUT_H 7
#define OUT_W 7
#define GS 2                      // SAMPLE_NUM
#define NBINS (OUT_H * OUT_W)     // 49
#define NSAMP (GS * GS)           // 4
#define SPATIAL_SCALE 0.25f
#define B_ 2
#define C_ 256
#define H_ 200
#define W_ 200
#define R_ 1000
#define HW_ (H_ * W_)             // 40000

// ============================================================================
// Fast path: NHWC transform + channel-coalesced gather
// ============================================================================

// ---- NCHW -> NHWC tiled transpose (per batch: [C, HW] -> [HW, C]) ----
// tile: 32 channels x 64 hw positions. block = 256 threads.
__global__ __launch_bounds__(256)
void nchw_to_nhwc(const float* __restrict__ in, float* __restrict__ out) {
    __shared__ float tile[32][65];   // [c_local][hw_local], pad -> conflict-free
    const int hw0 = blockIdx.x * 64;     // 40000/64 = 625 tiles
    const int c0  = blockIdx.y * 32;     // 256/32   = 8 tiles
    const int b   = blockIdx.z;

    // read phase: lanes along hw (coalesced 256B per wave-load)
    {
        const int tx = threadIdx.x & 63;      // hw within tile
        const int ty = threadIdx.x >> 6;      // 0..3 (c rows, step 4)
        const float* ip = in + ((size_t)b * C_ + c0) * HW_ + hw0;
#pragma unroll
        for (int k = 0; k < 8; ++k)
            tile[ty + 4 * k][tx] = ip[(size_t)(ty + 4 * k) * HW_ + tx];
    }
    __syncthreads();
    // write phase: lanes along c (coalesced)
    {
        const int tx = threadIdx.x & 31;      // c within tile
        const int ty = threadIdx.x >> 5;      // 0..7 (hw rows, step 8)
        float* op = out + ((size_t)b * HW_ + hw0) * C_ + c0;
#pragma unroll
        for (int k = 0; k < 8; ++k)
            op[(size_t)(ty + 8 * k) * C_ + tx] = tile[tx][ty + 8 * k];
    }
}

// ---- gather from NHWC: one block per roi, one wave per bin ----
// Each lane covers 4 channels (float4). 16 taps/bin, each tap is one
// fully-coalesced 1KB wave-load. Output staged in LDS, written contiguously.
__global__ __launch_bounds__(256)
void gather_nhwc(const float* __restrict__ nhwc,
                 const float* __restrict__ rois,
                 float* __restrict__ out) {
    __shared__ float obuf[C_ * NBINS];   // 12544 floats = 49.2 KB, flat [c][bin]

    const int r    = blockIdx.x;
    const int wave = threadIdx.x >> 6;
    const int lane = threadIdx.x & 63;

    const float* roi = rois + r * 6;
    const int   b     = (int)roi[0];
    const float cx    = roi[1] * SPATIAL_SCALE - 0.5f;   // ALIGNED
    const float cy    = roi[2] * SPATIAL_SCALE - 0.5f;
    const float rw    = roi[3] * SPATIAL_SCALE;
    const float rh    = roi[4] * SPATIAL_SCALE;
    const float theta = roi[5];                           // CLOCKWISE == False
    const float bin_h = rh * (1.0f / OUT_H);
    const float bin_w = rw * (1.0f / OUT_W);
    float st, ct;
    __sincosf(theta, &st, &ct);

    const size_t bplane = (size_t)b * HW_;

    for (int bin = wave; bin < NBINS; bin += 4) {
        const int ph = bin / OUT_W, pw = bin % OUT_W;
        float accx = 0.0f, accy = 0.0f, accz = 0.0f, accw = 0.0f;

#pragma unroll
        for (int s = 0; s < NSAMP; ++s) {
            const int iy = s >> 1, ix = s & 1;
            const float yy = -rh * 0.5f + ((float)ph + ((float)iy + 0.5f) * 0.5f) * bin_h;
            const float xx = -rw * 0.5f + ((float)pw + ((float)ix + 0.5f) * 0.5f) * bin_w;
            float x = yy * st + xx * ct + cx;
            float y = yy * ct - xx * st + cy;

            const bool valid = (y > -1.0f) && (y < (float)H_) &&
                               (x > -1.0f) && (x < (float)W_);
            y = fmaxf(y, 0.0f);
            x = fmaxf(x, 0.0f);
            int yl = (int)y, xl = (int)x;
            int yh; float ly;
            if (yl >= H_ - 1) { yl = H_ - 1; yh = H_ - 1; ly = 0.0f; }
            else              { yh = yl + 1; ly = y - (float)yl; }
            int xh; float lx;
            if (xl >= W_ - 1) { xl = W_ - 1; xh = W_ - 1; lx = 0.0f; }
            else              { xh = xl + 1; lx = x - (float)xl; }
            const float hy = 1.0f - ly, hx = 1.0f - lx;
            const float scale = valid ? (1.0f / NSAMP) : 0.0f;
            const float w0 = hy * hx * scale, w1 = hy * lx * scale;
            const float w2 = ly * hx * scale, w3 = ly * lx * scale;

            const size_t p0 = bplane + (size_t)yl * W_ + xl;
            const size_t p1 = bplane + (size_t)yl * W_ + xh;
            const size_t p2 = bplane + (size_t)yh * W_ + xl;
            const size_t p3 = bplane + (size_t)yh * W_ + xh;

            const float4 v0 = ((const float4*)nhwc)[p0 * (C_ / 4) + lane];
            const float4 v1 = ((const float4*)nhwc)[p1 * (C_ / 4) + lane];
            const float4 v2 = ((const float4*)nhwc)[p2 * (C_ / 4) + lane];
            const float4 v3 = ((const float4*)nhwc)[p3 * (C_ / 4) + lane];

            accx += w0 * v0.x + w1 * v1.x + w2 * v2.x + w3 * v3.x;
            accy += w0 * v0.y + w1 * v1.y + w2 * v2.y + w3 * v3.y;
            accz += w0 * v0.z + w1 * v1.z + w2 * v2.z + w3 * v3.z;
            accw += w0 * v0.w + w1 * v1.w + w2 * v2.w + w3 * v3.w;
        }

        // stage into LDS at flat [c][bin] (matches out flat layout per roi)
        const int c0 = lane * 4;
        obuf[(c0 + 0) * NBINS + bin] = accx;
        obuf[(c0 + 1) * NBINS + bin] = accy;
        obuf[(c0 + 2) * NBINS + bin] = accz;
        obuf[(c0 + 3) * NBINS + bin] = accw;
    }
    __syncthreads();

    // contiguous coalesced writeout: out[r][c][bin] flat == obuf flat
    float* o = out + (size_t)r * (C_ * NBINS);
#pragma unroll
    for (int t = threadIdx.x; t < C_ * NBINS; t += 256)
        o[t] = obuf[t];
}

// ============================================================================
// Fallback paths (round-0 structure, known-passing)
// ============================================================================

struct alignas(16) Samp {
    int o0, o1, o2, o3;
    float w0, w1, w2, w3;
};

__device__ __forceinline__ Samp compute_samp(const float* __restrict__ rois,
                                             int r, int ph, int pw, int s) {
    const float* roi = rois + r * 6;
    int   b     = (int)roi[0];
    float cx    = roi[1] * SPATIAL_SCALE - 0.5f;
    float cy    = roi[2] * SPATIAL_SCALE - 0.5f;
    float rw    = roi[3] * SPATIAL_SCALE;
    float rh    = roi[4] * SPATIAL_SCALE;
    float theta = roi[5];
    float bin_h = rh * (1.0f / OUT_H);
    float bin_w = rw * (1.0f / OUT_W);
    int iy = s / GS, ix = s % GS;
    float yy = -rh * 0.5f + ((float)ph + ((float)iy + 0.5f) * (1.0f / GS)) * bin_h;
    float xx = -rw * 0.5f + ((float)pw + ((float)ix + 0.5f) * (1.0f / GS)) * bin_w;
    float st = sinf(theta), ct = cosf(theta);
    float x = yy * st + xx * ct + cx;
    float y = yy * ct - xx * st + cy;
    bool valid = (y > -1.0f) && (y < (float)H_) && (x > -1.0f) && (x < (float)W_);
    y = fmaxf(y, 0.0f);
    x = fmaxf(x, 0.0f);
    int yl = (int)y;
    int xl = (int)x;
    int yh; float ly;
    if (yl >= H_ - 1) { yl = H_ - 1; yh = H_ - 1; ly = 0.0f; }
    else              { yh = yl + 1; ly = y - (float)yl; }
    int xh; float lx;
    if (xl >= W_ - 1) { xl = W_ - 1; xh = W_ - 1; lx = 0.0f; }
    else              { xh = xl + 1; lx = x - (float)xl; }
    float hy = 1.0f - ly, hx = 1.0f - lx;
    float scale = valid ? (1.0f / NSAMP) : 0.0f;
    Samp sp;
    int base = b * (C_ * H_ * W_);
    sp.o0 = base + yl * W_ + xl;
    sp.o1 = base + yl * W_ + xh;
    sp.o2 = base + yh * W_ + xl;
    sp.o3 = base + yh * W_ + xh;
    sp.w0 = hy * hx * scale;
    sp.w1 = hy * lx * scale;
    sp.w2 = ly * hx * scale;
    sp.w3 = ly * lx * scale;
    return sp;
}

__global__ __launch_bounds__(256)
void mono_kernel(const float* __restrict__ feat,
                 const float* __restrict__ rois,
                 float* __restrict__ out) {
    int tid = blockIdx.x * blockDim.x + threadIdx.x;
    if (tid >= R_ * C_ * NBINS) return;
    int bin = tid % NBINS;
    int rc  = tid / NBINS;
    int c   = rc % C_;
    int r   = rc / C_;
    int coff = c * (H_ * W_);
    float acc = 0.0f;
#pragma unroll
    for (int s = 0; s < NSAMP; ++s) {
        Samp t = compute_samp(rois, r, bin / OUT_W, bin % OUT_W, s);
        acc += t.w0 * feat[coff + t.o0];
        acc += t.w1 * feat[coff + t.o1];
        acc += t.w2 * feat[coff + t.o2];
        acc += t.w3 * feat[coff + t.o3];
    }
    out[tid] = acc;
}

// ============================================================================

extern "C" void kernel_launch(void* const* d_in, const int* in_sizes, int n_in,
                              void* d_out, int out_size, void* d_ws, size_t ws_size,
                              hipStream_t stream) {
    const float* feat = (const float*)d_in[0];
    const float* rois = (const float*)d_in[1];
    float* out = (float*)d_out;

    const size_t nhwc_bytes = (size_t)B_ * C_ * HW_ * sizeof(float);  // 81.92 MB

    if (ws_size >= nhwc_bytes) {
        float* nhwc = (float*)d_ws;
        dim3 tgrid(HW_ / 64, C_ / 32, B_);   // 625 x 8 x 2
        nchw_to_nhwc<<<tgrid, 256, 0, stream>>>(feat, nhwc);
        gather_nhwc<<<R_, 256, 0, stream>>>(nhwc, rois, out);
    } else {
        const int n_out = R_ * C_ * NBINS;
        mono_kernel<<<(n_out + 255) / 256, 256, 0, stream>>>(feat, rois, out);
    }
}

// Round 3
// 212.467 us; speedup vs baseline: 2.1986x; 1.0317x over previous
//
#include <hip/hip_runtime.h>
#include <math.h>

// Problem constants (fixed by the reference file)
#define OUT_H 7
#define OUT_W 7
#define GS 2                      // SAMPLE_NUM
#define NBINS (OUT_H * OUT_W)     // 49
#define NSAMP (GS * GS)           // 4
#define SPATIAL_SCALE 0.25f
#define B_ 2
#define C_ 256
#define H_ 200
#define W_ 200
#define R_ 1000
#define HW_ (H_ * W_)             // 40000

// ============================================================================
// Fast path: NHWC transform + channel-coalesced gather
// ============================================================================

// ---- NCHW -> NHWC tiled transpose (per batch: [C, HW] -> [HW, C]) ----
// tile: 32 channels x 64 hw positions. block = 256 threads. (known-good R2)
__global__ __launch_bounds__(256)
void nchw_to_nhwc(const float* __restrict__ in, float* __restrict__ out) {
    __shared__ float tile[32][65];   // [c_local][hw_local], pad -> conflict-free
    const int hw0 = blockIdx.x * 64;     // 40000/64 = 625 tiles
    const int c0  = blockIdx.y * 32;     // 256/32   = 8 tiles
    const int b   = blockIdx.z;

    // read phase: lanes along hw (coalesced 256B per wave-load)
    {
        const int tx = threadIdx.x & 63;      // hw within tile
        const int ty = threadIdx.x >> 6;      // 0..3 (c rows, step 4)
        const float* ip = in + ((size_t)b * C_ + c0) * HW_ + hw0;
#pragma unroll
        for (int k = 0; k < 8; ++k)
            tile[ty + 4 * k][tx] = ip[(size_t)(ty + 4 * k) * HW_ + tx];
    }
    __syncthreads();
    // write phase: lanes along c (coalesced)
    {
        const int tx = threadIdx.x & 31;      // c within tile
        const int ty = threadIdx.x >> 5;      // 0..7 (hw rows, step 8)
        float* op = out + ((size_t)b * HW_ + hw0) * C_ + c0;
#pragma unroll
        for (int k = 0; k < 8; ++k)
            op[(size_t)(ty + 8 * k) * C_ + tx] = tile[tx][ty + 8 * k];
    }
}

// ---- gather from NHWC: one block (512 thr, 8 waves) per roi ----
// wave = bin stripe; lane covers channels 4*lane..4*lane+3 (float4 taps).
// 16 taps/bin, each a fully-coalesced 1KB wave-load. Output staged in LDS
// (conflict-free plane layout), streamed out with nontemporal dword stores.
__global__ __launch_bounds__(512)
void gather_nhwc(const float* __restrict__ nhwc,
                 const float* __restrict__ rois,
                 float* __restrict__ out) {
    // [k][c4][bin]: element (c,bin) lives at obuf[(c&3)*3136 + (c>>2)*49 + bin]
    __shared__ float obuf[4 * 64 * NBINS];   // 50176 B

    const int r    = blockIdx.x;
    const int wave = threadIdx.x >> 6;   // 0..7
    const int lane = threadIdx.x & 63;

    const float* roi = rois + r * 6;
    const int   b     = (int)roi[0];
    const float cx    = roi[1] * SPATIAL_SCALE - 0.5f;   // ALIGNED
    const float cy    = roi[2] * SPATIAL_SCALE - 0.5f;
    const float rw    = roi[3] * SPATIAL_SCALE;
    const float rh    = roi[4] * SPATIAL_SCALE;
    const float theta = roi[5];                           // CLOCKWISE == False
    const float bin_h = rh * (1.0f / OUT_H);
    const float bin_w = rw * (1.0f / OUT_W);
    float st, ct;
    __sincosf(theta, &st, &ct);

    const int bplane = b * HW_;            // pixel-index base (fits int)
    const float4* __restrict__ fp = (const float4*)nhwc;

    for (int bin = wave; bin < NBINS; bin += 8) {
        const int ph = bin / OUT_W, pw = bin % OUT_W;
        float accx = 0.0f, accy = 0.0f, accz = 0.0f, accw = 0.0f;

#pragma unroll
        for (int s = 0; s < NSAMP; ++s) {
            const int iy = s >> 1, ix = s & 1;
            const float yy = -rh * 0.5f + ((float)ph + ((float)iy + 0.5f) * 0.5f) * bin_h;
            const float xx = -rw * 0.5f + ((float)pw + ((float)ix + 0.5f) * 0.5f) * bin_w;
            float x = yy * st + xx * ct + cx;
            float y = yy * ct - xx * st + cy;

            const bool valid = (y > -1.0f) && (y < (float)H_) &&
                               (x > -1.0f) && (x < (float)W_);
            y = fmaxf(y, 0.0f);
            x = fmaxf(x, 0.0f);
            int yl = (int)y, xl = (int)x;
            int yh; float ly;
            if (yl >= H_ - 1) { yl = H_ - 1; yh = H_ - 1; ly = 0.0f; }
            else              { yh = yl + 1; ly = y - (float)yl; }
            int xh; float lx;
            if (xl >= W_ - 1) { xl = W_ - 1; xh = W_ - 1; lx = 0.0f; }
            else              { xh = xl + 1; lx = x - (float)xl; }
            const float hy = 1.0f - ly, hx = 1.0f - lx;
            const float scale = valid ? (1.0f / NSAMP) : 0.0f;
            const float w0 = hy * hx * scale, w1 = hy * lx * scale;
            const float w2 = ly * hx * scale, w3 = ly * lx * scale;

            const int p0 = bplane + yl * W_ + xl;
            const int p1 = bplane + yl * W_ + xh;
            const int p2 = bplane + yh * W_ + xl;
            const int p3 = bplane + yh * W_ + xh;

            const float4 v0 = fp[p0 * (C_ / 4) + lane];
            const float4 v1 = fp[p1 * (C_ / 4) + lane];
            const float4 v2 = fp[p2 * (C_ / 4) + lane];
            const float4 v3 = fp[p3 * (C_ / 4) + lane];

            accx += w0 * v0.x + w1 * v1.x + w2 * v2.x + w3 * v3.x;
            accy += w0 * v0.y + w1 * v1.y + w2 * v2.y + w3 * v3.y;
            accz += w0 * v0.z + w1 * v1.z + w2 * v2.z + w3 * v3.z;
            accw += w0 * v0.w + w1 * v1.w + w2 * v2.w + w3 * v3.w;
        }

        // conflict-free staging: bank = (17*lane + bin) % 32 -> 2-way (free)
        obuf[0 * 3136 + lane * NBINS + bin] = accx;   // c = 4*lane+0
        obuf[1 * 3136 + lane * NBINS + bin] = accy;   // c = 4*lane+1
        obuf[2 * 3136 + lane * NBINS + bin] = accz;   // c = 4*lane+2
        obuf[3 * 3136 + lane * NBINS + bin] = accw;   // c = 4*lane+3
    }
    __syncthreads();

    // writeout: out[r][c][bin] flat; lane-contiguous t -> conflict-free LDS
    // reads + fully-coalesced nontemporal dword stores (output bypasses L2).
    float* o = out + (size_t)r * (C_ * NBINS);
#pragma unroll
    for (int i = 0; i < 25; ++i) {
        const int t = threadIdx.x + 512 * i;
        if (t < C_ * NBINS) {
            const unsigned c   = (unsigned)t / 49u;
            const unsigned bin = (unsigned)t - 49u * c;
            const float v = obuf[(c & 3u) * 3136u + (c >> 2) * 49u + bin];
            __builtin_nontemporal_store(v, &o[t]);
        }
    }
}

// ============================================================================
// Fallback path (round-0 structure, known-passing)
// ============================================================================

struct alignas(16) Samp {
    int o0, o1, o2, o3;
    float w0, w1, w2, w3;
};

__device__ __forceinline__ Samp compute_samp(const float* __restrict__ rois,
                                             int r, int ph, int pw, int s) {
    const float* roi = rois + r * 6;
    int   b     = (int)roi[0];
    float cx    = roi[1] * SPATIAL_SCALE - 0.5f;
    float cy    = roi[2] * SPATIAL_SCALE - 0.5f;
    float rw    = roi[3] * SPATIAL_SCALE;
    float rh    = roi[4] * SPATIAL_SCALE;
    float theta = roi[5];
    float bin_h = rh * (1.0f / OUT_H);
    float bin_w = rw * (1.0f / OUT_W);
    int iy = s / GS, ix = s % GS;
    float yy = -rh * 0.5f + ((float)ph + ((float)iy + 0.5f) * (1.0f / GS)) * bin_h;
    float xx = -rw * 0.5f + ((float)pw + ((float)ix + 0.5f) * (1.0f / GS)) * bin_w;
    float st = sinf(theta), ct = cosf(theta);
    float x = yy * st + xx * ct + cx;
    float y = yy * ct - xx * st + cy;
    bool valid = (y > -1.0f) && (y < (float)H_) && (x > -1.0f) && (x < (float)W_);
    y = fmaxf(y, 0.0f);
    x = fmaxf(x, 0.0f);
    int yl = (int)y;
    int xl = (int)x;
    int yh; float ly;
    if (yl >= H_ - 1) { yl = H_ - 1; yh = H_ - 1; ly = 0.0f; }
    else              { yh = yl + 1; ly = y - (float)yl; }
    int xh; float lx;
    if (xl >= W_ - 1) { xl = W_ - 1; xh = W_ - 1; lx = 0.0f; }
    else              { xh = xl + 1; lx = x - (float)xl; }
    float hy = 1.0f - ly, hx = 1.0f - lx;
    float scale = valid ? (1.0f / NSAMP) : 0.0f;
    Samp sp;
    int base = b * (C_ * H_ * W_);
    sp.o0 = base + yl * W_ + xl;
    sp.o1 = base + yl * W_ + xh;
    sp.o2 = base + yh * W_ + xl;
    sp.o3 = base + yh * W_ + xh;
    sp.w0 = hy * hx * scale;
    sp.w1 = hy * lx * scale;
    sp.w2 = ly * hx * scale;
    sp.w3 = ly * lx * scale;
    return sp;
}

__global__ __launch_bounds__(256)
void mono_kernel(const float* __restrict__ feat,
                 const float* __restrict__ rois,
                 float* __restrict__ out) {
    int tid = blockIdx.x * blockDim.x + threadIdx.x;
    if (tid >= R_ * C_ * NBINS) return;
    int bin = tid % NBINS;
    int rc  = tid / NBINS;
    int c   = rc % C_;
    int r   = rc / C_;
    int coff = c * (H_ * W_);
    float acc = 0.0f;
#pragma unroll
    for (int s = 0; s < NSAMP; ++s) {
        Samp t = compute_samp(rois, r, bin / OUT_W, bin % OUT_W, s);
        acc += t.w0 * feat[coff + t.o0];
        acc += t.w1 * feat[coff + t.o1];
        acc += t.w2 * feat[coff + t.o2];
        acc += t.w3 * feat[coff + t.o3];
    }
    out[tid] = acc;
}

// ============================================================================

extern "C" void kernel_launch(void* const* d_in, const int* in_sizes, int n_in,
                              void* d_out, int out_size, void* d_ws, size_t ws_size,
                              hipStream_t stream) {
    const float* feat = (const float*)d_in[0];
    const float* rois = (const float*)d_in[1];
    float* out = (float*)d_out;

    const size_t nhwc_bytes = (size_t)B_ * C_ * HW_ * sizeof(float);  // 81.92 MB

    if (ws_size >= nhwc_bytes) {
        float* nhwc = (float*)d_ws;
        dim3 tgrid(HW_ / 64, C_ / 32, B_);   // 625 x 8 x 2
        nchw_to_nhwc<<<tgrid, 256, 0, stream>>>(feat, nhwc);
        gather_nhwc<<<R_, 512, 0, stream>>>(nhwc, rois, out);
    } else {
        const int n_out = R_ * C_ * NBINS;
        mono_kernel<<<(n_out + 255) / 256, 256, 0, stream>>>(feat, rois, out);
    }
}